// Round 6
// baseline (383.965 us; speedup 1.0000x reference)
//
#include <hip/hip_runtime.h>
#include <hip/hip_bf16.h>

#define NH   32
#define NKV  8
#define HD   128
#define SL   2048
#define HID  4096
#define KVW  1024   // NKV*HD
#define QKVN 6144   // HID + 2*KVW

typedef __attribute__((ext_vector_type(8))) short short8;
typedef __attribute__((ext_vector_type(4))) float f32x4;

static __device__ __forceinline__ unsigned short f2bf(float f){
  union { float f; unsigned int i; } v; v.f = f;
  unsigned int r = v.i + 0x7FFFu + ((v.i >> 16) & 1u);
  return (unsigned short)(r >> 16);
}
static __device__ __forceinline__ float bf2f(unsigned short u){
  union { unsigned int i; float f; } v; v.i = ((unsigned int)u) << 16; return v.f;
}
static __device__ __forceinline__ unsigned int pack2(float lo, float hi){
  return (unsigned int)f2bf(lo) | ((unsigned int)f2bf(hi) << 16);
}
static __device__ __forceinline__ unsigned int cvtpk(float lo, float hi){
  unsigned int d;
  asm("v_cvt_pk_bf16_f32 %0, %1, %2" : "=v"(d) : "v"(lo), "v"(hi));
  return d;
}

// async global -> LDS, 16 B per lane. LDS dest is wave-uniform base + lane*16;
// global source is per-lane.
static __device__ __forceinline__ void gload_lds16(const void* g, void* l){
  __builtin_amdgcn_global_load_lds(
      (const __attribute__((address_space(1))) void*)g,
      (__attribute__((address_space(3))) void*)l,
      16, 0, 0);
}

// ---------------- cast fp32 -> bf16, 8 elems/thread ----------------
__global__ void cast_f32_bf16(const float* __restrict__ src, uint4* __restrict__ dst, int n8){
  int stride = gridDim.x * blockDim.x;
  for (int i = blockIdx.x * blockDim.x + threadIdx.x; i < n8; i += stride){
    float4 a = ((const float4*)src)[2*i + 0];
    float4 b = ((const float4*)src)[2*i + 1];
    uint4 o;
    o.x = pack2(a.x, a.y); o.y = pack2(a.z, a.w);
    o.z = pack2(b.x, b.y); o.w = pack2(b.z, b.w);
    dst[i] = o;
  }
}

// ---------------- RoPE cos/sin table ----------------
__global__ void rope_table_kernel(const int* __restrict__ pos, float2* __restrict__ tab){
  int i = blockIdx.x * blockDim.x + threadIdx.x;
  if (i >= SL * 64) return;
  int s = i >> 6, f = i & 63;
  float inv = expf(-((float)(2 * f) / 128.0f) * 9.210340371976184f);
  float ang = (float)pos[s] * inv;
  float sn, cs;
  sincosf(ang, &sn, &cs);
  tab[i] = make_float2(cs, sn);
}

// ---------------- in-place RoPE on bf16 [s][stride] ----------------
__global__ void rope_apply_kernel(unsigned short* x, const float2* __restrict__ tab,
                                  int nheads, int rowstride){
  int i = blockIdx.x * blockDim.x + threadIdx.x;
  int total = SL * nheads * 64;
  if (i >= total) return;
  int f = i & 63;
  int t = i >> 6;
  int h = t % nheads;
  int s = t / nheads;
  float2 cs = tab[s * 64 + f];
  size_t base = (size_t)s * rowstride + h * HD;
  float x1 = bf2f(x[base + f]);
  float x2 = bf2f(x[base + f + 64]);
  x[base + f]      = f2bf(x1 * cs.x - x2 * cs.y);
  x[base + f + 64] = f2bf(x2 * cs.x + x1 * cs.y);
}

// ================= 8-phase bt-GEMM (m201-style): C = A * B^T =================
// BN=256, BK=64, 8 waves (2M x 4N). BM=256: per-wave 128x64, 4 phases x 16 MFMA.
// BM=128: per-wave 64x64, 2 phases x 16 MFMA. Double-buffered LDS; XOR-swizzled
// layout (slot ^= row&7) via inverse-swizzled per-lane GLOBAL source + swizzled
// ds_read (linear gload_lds dest). Counted vmcnt at phase 0 only (never drains
// mid-loop). setprio(1) around each MFMA cluster.
template<int BM, bool F32OUT>
__global__ __launch_bounds__(512, 2) void gemm_bt8(
  const unsigned short* __restrict__ A,
  const unsigned short* __restrict__ B,
  void* __restrict__ Cp, int M, int N, int K)
{
  constexpr int BN = 256;
  constexpr int MF = BM / 32;              // M-frags per wave (8 or 4)
  __shared__ __align__(16) unsigned short As[2 * BM * 64];
  __shared__ __align__(16) unsigned short Bs[2 * BN * 64];
  const int tid = threadIdx.x;
  const int lane = tid & 63, wid = tid >> 6;
  const int g = lane >> 4, c15 = lane & 15;
  const int wr = wid >> 2, wn = wid & 3;   // 2 x 4 wave grid

  // ---- 2D rect XCD swizzle ----
  const int gx = gridDim.x, gy = gridDim.y;
  const int nwg = gx * gy;
  const int lin = blockIdx.y * gx + blockIdx.x;
  int mb, nb;
  const int cpx = nwg >> 3;
  const int RN  = cpx >> 3;
  if (RN > 0 && (gy & 7) == 0 && (cpx & 7) == 0 && gx % RN == 0 && (8 % (gx / RN)) == 0){
    int xcd = lin & 7, j = lin >> 3;
    int nrc = gx / RN;
    int rr = xcd / nrc, rc = xcd % nrc;
    mb = rr * 8 + (j & 7);
    nb = rc * RN + (j >> 3);
  } else { mb = lin / gx; nb = lin % gx; }
  const int m0 = mb * BM, n0 = nb * BN;

  // staging: per wave, A covers BM/8 rows (BM/64 chunks of 8 rows), B covers 32
  // rows (4 chunks). Chunk = 8 rows x 128B; lane l -> row l>>3, 16B slot l&7.
  // Global source pre-applies the inverse swizzle: slot_g = (l&7) ^ (l>>3).
  const int lr = lane >> 3;
  const int ls = (lane & 7) ^ lr;
  const unsigned short* Agl = A + (size_t)(m0 + wid * (BM / 8) + lr) * K + ls * 8;
  const unsigned short* Bgl = B + (size_t)(n0 + wid * 32 + lr) * K + ls * 8;
  unsigned short* AsW = As + wid * (BM / 8) * 64;
  unsigned short* BsW = Bs + wid * 32 * 64;

  auto STA = [&](int b, int q, int tt){
    gload_lds16(Agl + (size_t)q * 8 * K + tt * 64, AsW + b * BM * 64 + q * 512);
  };
  auto STB = [&](int b, int q, int tt){
    gload_lds16(Bgl + (size_t)q * 8 * K + tt * 64, BsW + b * BN * 64 + q * 512);
  };
  // swizzled fragment reads: physical slot = logical slot ^ (row&7)
  auto ldA = [&](int b, int fm, int kk) -> short8 {
    return *(const short8*)((const char*)As + (size_t)b * BM * 128 +
           (wr * (BM / 2) + fm * 16 + c15) * 128 +
           ((kk * 64 + g * 16) ^ ((c15 & 7) << 4)));
  };
  auto ldB = [&](int b, int fn, int kk) -> short8 {
    return *(const short8*)((const char*)Bs + (size_t)b * BN * 128 +
           (wn * 64 + fn * 16 + c15) * 128 +
           ((kk * 64 + g * 16) ^ ((c15 & 7) << 4)));
  };

  f32x4 acc[MF][4] = {};

  // prologue: stage tile 0 into buffer 0 (BM/64 + 4 issues per wave)
#pragma unroll
  for (int q = 0; q < BM / 64; ++q) STA(0, q, 0);
#pragma unroll
  for (int q = 0; q < 4; ++q) STB(0, q, 0);

  const int nk = K >> 6;
  for (int t = 0; t < nk; ++t){
    const int cur = t & 1, nxt = cur ^ 1;
    const bool pf = (t + 1 < nk);
    const int t1 = t + 1;
    short8 af[4], bf[4];

    // ---------- phase 0: kk=0, m-half 0 ----------
    if (pf){
      STA(nxt, 0, t1); STA(nxt, 1, t1);
      if constexpr (BM == 128){
        STB(nxt, 0, t1);
        asm volatile("s_waitcnt vmcnt(3)" ::: "memory");
      } else {
        asm volatile("s_waitcnt vmcnt(2)" ::: "memory");
      }
    } else {
      asm volatile("s_waitcnt vmcnt(0)" ::: "memory");
    }
    __builtin_amdgcn_s_barrier();
#pragma unroll
    for (int m = 0; m < 4; ++m) af[m] = ldA(cur, m, 0);
#pragma unroll
    for (int n = 0; n < 4; ++n) bf[n] = ldB(cur, n, 0);
    __builtin_amdgcn_s_setprio(1);
#pragma unroll
    for (int m = 0; m < 4; ++m)
#pragma unroll
      for (int n = 0; n < 4; ++n)
        acc[m][n] = __builtin_amdgcn_mfma_f32_16x16x32_bf16(af[m], bf[n], acc[m][n], 0, 0, 0);
    __builtin_amdgcn_s_setprio(0);
    __builtin_amdgcn_s_barrier();

    if constexpr (BM == 256){
      // ---------- phase 1: kk=0, m-half 1 (reuse bf) ----------
#pragma unroll
      for (int m = 0; m < 4; ++m) af[m] = ldA(cur, 4 + m, 0);
      if (pf){ STA(nxt, 2, t1); STA(nxt, 3, t1); }
      __builtin_amdgcn_s_barrier();
      __builtin_amdgcn_s_setprio(1);
#pragma unroll
      for (int m = 0; m < 4; ++m)
#pragma unroll
        for (int n = 0; n < 4; ++n)
          acc[4 + m][n] = __builtin_amdgcn_mfma_f32_16x16x32_bf16(af[m], bf[n], acc[4 + m][n], 0, 0, 0);
      __builtin_amdgcn_s_setprio(0);
      __builtin_amdgcn_s_barrier();
    }

    // ---------- phase 2: kk=1, m-half 0 ----------
#pragma unroll
    for (int m = 0; m < 4; ++m) af[m] = ldA(cur, m, 1);
#pragma unroll
    for (int n = 0; n < 4; ++n) bf[n] = ldB(cur, n, 1);
    if (pf){
      if constexpr (BM == 256){ STB(nxt, 0, t1); STB(nxt, 1, t1); }
      else                    { STB(nxt, 1, t1); STB(nxt, 2, t1); STB(nxt, 3, t1); }
    }
    __builtin_amdgcn_s_barrier();
    __builtin_amdgcn_s_setprio(1);
#pragma unroll
    for (int m = 0; m < 4; ++m)
#pragma unroll
      for (int n = 0; n < 4; ++n)
        acc[m][n] = __builtin_amdgcn_mfma_f32_16x16x32_bf16(af[m], bf[n], acc[m][n], 0, 0, 0);
    __builtin_amdgcn_s_setprio(0);
    __builtin_amdgcn_s_barrier();

    if constexpr (BM == 256){
      // ---------- phase 3: kk=1, m-half 1 ----------
#pragma unroll
      for (int m = 0; m < 4; ++m) af[m] = ldA(cur, 4 + m, 1);
      if (pf){ STB(nxt, 2, t1); STB(nxt, 3, t1); }
      __builtin_amdgcn_s_barrier();
      __builtin_amdgcn_s_setprio(1);
#pragma unroll
      for (int m = 0; m < 4; ++m)
#pragma unroll
        for (int n = 0; n < 4; ++n)
          acc[4 + m][n] = __builtin_amdgcn_mfma_f32_16x16x32_bf16(af[m], bf[n], acc[4 + m][n], 0, 0, 0);
      __builtin_amdgcn_s_setprio(0);
      __builtin_amdgcn_s_barrier();
    }
  }

  // epilogue
#pragma unroll
  for (int m = 0; m < MF; ++m)
#pragma unroll
    for (int n = 0; n < 4; ++n){
      int row = m0 + wr * (BM / 2) + m * 16 + g * 4;
      int col = n0 + wn * 64 + n * 16 + c15;
      f32x4 v = acc[m][n];
      if (F32OUT){
        float* C = (float*)Cp;
#pragma unroll
        for (int r = 0; r < 4; ++r) C[(size_t)(row + r) * N + col] = v[r];
      } else {
        unsigned short* C = (unsigned short*)Cp;
#pragma unroll
        for (int r = 0; r < 4; ++r) C[(size_t)(row + r) * N + col] = f2bf(v[r]);
      }
    }
}

// ---------------- V transpose: v[s][h*128+d] (stride vstride) -> vt[h][d][s] ----------------
__global__ void transpose_v_kernel(const unsigned short* __restrict__ v, int vstride,
                                   unsigned short* __restrict__ vt){
  __shared__ unsigned short t[64][65];
  int h  = blockIdx.z;
  int d0 = blockIdx.y * 64;
  int s0 = blockIdx.x * 64;
  int c  = threadIdx.x & 63;
  int r0 = threadIdx.x >> 6;
#pragma unroll
  for (int r = r0; r < 64; r += 4) t[r][c] = v[(size_t)(s0 + r) * vstride + h * HD + d0 + c];
  __syncthreads();
#pragma unroll
  for (int r = r0; r < 64; r += 4) vt[(size_t)(h * HD + d0 + r) * SL + s0 + c] = t[c][r];
}

// ---------------- flash attention: swapped-QK in-register softmax ----------------
__global__ __launch_bounds__(512, 4) void flash_attn_kernel(
  const unsigned short* __restrict__ Q,    // row stride QKVN
  const unsigned short* __restrict__ Kb,   // row stride QKVN
  const unsigned short* __restrict__ Vt,   // [kvh*128+d][SL]
  unsigned short* __restrict__ O)          // row stride HID
{
  __shared__ __align__(16) unsigned short Ks[64 * 128];    // stride 256 B, XOR-swizzled
  __shared__ __align__(16) unsigned short Vs[128 * 64];    // stride 128 B, XOR-swizzled
  const int tid = threadIdx.x, lane = tid & 63, wid = tid >> 6;
  const int g = lane >> 4, c15 = lane & 15;
  const int kvh = blockIdx.x;
  const int yy = blockIdx.y;
  const int qb = (yy & 1) ? (yy >> 1) : (63 - (yy >> 1));   // heavy/light interleave
  const int h = kvh * 4 + (wid & 3);
  const int rg = wid >> 2;
  const int q0 = qb * 32;
  const int qg = q0 + rg * 16 + c15;       // this lane's q row

  short8 aq[4];
  {
    size_t qrow = (size_t)qg * QKVN + h * HD;
#pragma unroll
    for (int kk = 0; kk < 4; ++kk)
      aq[kk] = *(const short8*)(&Q[qrow + kk * 32 + g * 8]);
  }

  const int krow = tid >> 3, kcol = (tid & 7) * 8;
  const int vrow = tid >> 2, vcol = (tid & 3) * 8;
  const unsigned short* Kgb = Kb + (size_t)kvh * HD;
  const unsigned short* Vgb = Vt + ((size_t)kvh * HD + vrow) * SL;

  uint4 kr0, kr1, vr0, vr1;
  {
    const unsigned short* kg = Kgb + (size_t)krow * QKVN + kcol;
    kr0 = *(const uint4*)kg; kr1 = *(const uint4*)(kg + 64);
    const unsigned short* vg = Vgb + vcol;
    vr0 = *(const uint4*)vg; vr1 = *(const uint4*)(vg + 32);
  }

  float m_i = -1e30f, l_i = 0.f;
  f32x4 oacc[8];
#pragma unroll
  for (int df = 0; df < 8; ++df) oacc[df] = (f32x4){0.f, 0.f, 0.f, 0.f};

  const float scl2 = 0.08838834764831845f * 1.4426950408889634f;  // 1/sqrt(128)*log2e
  const int nt = (q0 + 31) / 64 + 1;
  for (int kt = 0; kt < nt; ++kt){
    *(uint4*)((char*)Ks + krow * 256 + (( kcol * 2       ) ^ ((krow & 7) << 4))) = kr0;
    *(uint4*)((char*)Ks + krow * 256 + (((kcol * 2) + 128) ^ ((krow & 7) << 4))) = kr1;
    *(uint4*)((char*)Vs + vrow * 128 + (( vcol * 2       ) ^ ((vrow & 7) << 4))) = vr0;
    *(uint4*)((char*)Vs + vrow * 128 + (((vcol * 2) +  64) ^ ((vrow & 7) << 4))) = vr1;
    __syncthreads();

    if (kt + 1 < nt){
      const unsigned short* kg = Kgb + (size_t)((kt + 1) * 64 + krow) * QKVN + kcol;
      kr0 = *(const uint4*)kg; kr1 = *(const uint4*)(kg + 64);
      const unsigned short* vg = Vgb + (kt + 1) * 64 + vcol;
      vr0 = *(const uint4*)vg; vr1 = *(const uint4*)(vg + 32);
    }

    // S^T = K Q : lane holds q=c15, kv = f*16 + g*4 + r
    f32x4 sc[4];
    __builtin_amdgcn_s_setprio(1);
#pragma unroll
    for (int f = 0; f < 4; ++f){
      sc[f] = (f32x4){0.f, 0.f, 0.f, 0.f};
#pragma unroll
      for (int kk = 0; kk < 4; ++kk){
        short8 bk = *(const short8*)((const char*)Ks + (f * 16 + c15) * 256 +
                                     ((kk * 64 + g * 16) ^ ((c15 & 7) << 4)));
        sc[f] = __builtin_amdgcn_mfma_f32_16x16x32_bf16(bk, aq[kk], sc[f], 0, 0, 0);
      }
    }
    __builtin_amdgcn_s_setprio(0);

    float p[4][4];
#pragma unroll
    for (int f = 0; f < 4; ++f)
#pragma unroll
      for (int r = 0; r < 4; ++r){
        int kvg = kt * 64 + f * 16 + g * 4 + r;
        p[f][r] = (kvg <= qg) ? sc[f][r] * scl2 : -1e30f;
      }

    float pmax = p[0][0];
#pragma unroll
    for (int f = 0; f < 4; ++f)
#pragma unroll
      for (int r = 0; r < 4; ++r) pmax = fmaxf(pmax, p[f][r]);
    pmax = fmaxf(pmax, __shfl_xor(pmax, 16, 64));
    pmax = fmaxf(pmax, __shfl_xor(pmax, 32, 64));

    if (!__all(pmax - m_i <= 8.0f)){
      float mnew = fmaxf(m_i, pmax);
      float cf = exp2f(m_i - mnew);
      float cfr[4];
#pragma unroll
      for (int r = 0; r < 4; ++r) cfr[r] = __shfl(cf, (lane & 48) | (g * 4 + r), 64);
#pragma unroll
      for (int df = 0; df < 8; ++df)
#pragma unroll
        for (int r = 0; r < 4; ++r) oacc[df][r] *= cfr[r];
      l_i *= cf;
      m_i = mnew;
    }

    float lsum = 0.f;
#pragma unroll
    for (int f = 0; f < 4; ++f)
#pragma unroll
      for (int r = 0; r < 4; ++r){ float e = exp2f(p[f][r] - m_i); p[f][r] = e; lsum += e; }
    lsum += __shfl_xor(lsum, 16, 64);
    lsum += __shfl_xor(lsum, 32, 64);
    l_i += lsum;

    unsigned int pd[4][2];
#pragma unroll
    for (int f = 0; f < 4; ++f){
      pd[f][0] = cvtpk(p[f][0], p[f][1]);
      pd[f][1] = cvtpk(p[f][2], p[f][3]);
    }

    const int src0 = ((g & 1) << 5) | c15;
    const int src1 = src0 + 16;
    const bool hiF = (g >= 2);
#pragma unroll
    for (int kk = 0; kk < 2; ++kk){
      union { unsigned int u[4]; short8 s8; } pa;
#pragma unroll
      for (int pr = 0; pr < 2; ++pr){
        unsigned int a0 = __shfl((int)pd[2 * kk + 0][pr], src0, 64);
        unsigned int b0 = __shfl((int)pd[2 * kk + 1][pr], src0, 64);
        unsigned int a1 = __shfl((int)pd[2 * kk + 0][pr], src1, 64);
        unsigned int b1 = __shfl((int)pd[2 * kk + 1][pr], src1, 64);
        pa.u[pr]     = hiF ? b0 : a0;
        pa.u[2 + pr] = hiF ? b1 : a1;
      }
      __builtin_amdgcn_s_setprio(1);
#pragma unroll
      for (int df = 0; df < 8; ++df){
        short8 bv = *(const short8*)((const char*)Vs + (df * 16 + c15) * 128 +
                                     ((kk * 64 + g * 16) ^ ((c15 & 7) << 4)));
        oacc[df] = __builtin_amdgcn_mfma_f32_16x16x32_bf16(pa.s8, bv, oacc[df], 0, 0, 0);
      }
      __builtin_amdgcn_s_setprio(0);
    }
    __syncthreads();
  }

  float lr[4];
#pragma unroll
  for (int r = 0; r < 4; ++r) lr[r] = __shfl(l_i, (lane & 48) | (g * 4 + r), 64);
#pragma unroll
  for (int df = 0; df < 8; ++df)
#pragma unroll
    for (int r = 0; r < 4; ++r){
      int row = q0 + rg * 16 + g * 4 + r;
      O[(size_t)row * HID + h * HD + df * 16 + c15] = f2bf(oacc[df][r] / lr[r]);
    }
}

extern "C" void kernel_launch(void* const* d_in, const int* in_sizes, int n_in,
                              void* d_out, int out_size, void* d_ws, size_t ws_size,
                              hipStream_t stream)
{
  const float* hs  = (const float*)d_in[0];
  const float* qw  = (const float*)d_in[1];
  const float* kw  = (const float*)d_in[2];
  const float* vw  = (const float*)d_in[3];
  const float* ow  = (const float*)d_in[4];
  const int*   pos = (const int*)d_in[5];

  char* w = (char*)d_ws;
  auto alloc = [&](size_t bytes){ char* p = w; w += (bytes + 255) & ~(size_t)255; return p; };
  unsigned short* xb   = (unsigned short*)alloc((size_t)SL * HID * 2);
  unsigned short* wqkv = (unsigned short*)alloc((size_t)QKVN * HID * 2);
  unsigned short* owb  = (unsigned short*)alloc((size_t)HID * HID * 2);
  unsigned short* qkv  = (unsigned short*)alloc((size_t)SL * QKVN * 2);
  unsigned short* vt   = (unsigned short*)alloc((size_t)SL * KVW * 2);
  unsigned short* ab   = (unsigned short*)alloc((size_t)SL * HID * 2);
  float2*         tab  = (float2*)alloc((size_t)SL * 64 * sizeof(float2));

  auto cast = [&](const float* s, unsigned short* d, long n){
    int n8 = (int)(n / 8);
    int blocks = (n8 + 255) / 256; if (blocks > 2048) blocks = 2048;
    cast_f32_bf16<<<blocks, 256, 0, stream>>>(s, (uint4*)d, n8);
  };
  cast(hs, xb, (long)SL * HID);
  cast(qw, wqkv,                              (long)HID * HID);
  cast(kw, wqkv + (size_t)HID * HID,          (long)KVW * HID);
  cast(vw, wqkv + (size_t)(HID + KVW) * HID,  (long)KVW * HID);
  cast(ow, owb,                               (long)HID * HID);

  rope_table_kernel<<<(SL * 64 + 255) / 256, 256, 0, stream>>>(pos, tab);

  // fused QKV projection: [2048][6144] = xb @ wqkv^T  (grid 24 x 8 = 192)
  gemm_bt8<256, false><<<dim3(QKVN / 256, SL / 256), 512, 0, stream>>>(xb, wqkv, qkv, SL, QKVN, HID);

  rope_apply_kernel<<<(SL * NH  * 64 + 255) / 256, 256, 0, stream>>>(qkv,        tab, NH,  QKVN);
  rope_apply_kernel<<<(SL * NKV * 64 + 255) / 256, 256, 0, stream>>>(qkv + HID,  tab, NKV, QKVN);

  transpose_v_kernel<<<dim3(SL / 64, HD / 64, NKV), 256, 0, stream>>>(qkv + HID + KVW, QKVN, vt);

  flash_attn_kernel<<<dim3(NKV, SL / 32), 512, 0, stream>>>(qkv, qkv + HID, vt, ab);

  // O projection: [2048][4096]  (grid 16 x 16 = 256, 1 block/CU)
  gemm_bt8<128, true><<<dim3(HID / 256, SL / 128), 512, 0, stream>>>(ab, owb, d_out, SL, HID, HID);
}

// Round 7
// 371.747 us; speedup vs baseline: 1.0329x; 1.0329x over previous
//
#include <hip/hip_runtime.h>
#include <hip/hip_bf16.h>

#define NH   32
#define NKV  8
#define HD   128
#define SL   2048
#define HID  4096
#define KVW  1024   // NKV*HD
#define QKVN 6144   // HID + 2*KVW

typedef __attribute__((ext_vector_type(8))) short short8;
typedef __attribute__((ext_vector_type(4))) float f32x4;

static __device__ __forceinline__ unsigned short f2bf(float f){
  union { float f; unsigned int i; } v; v.f = f;
  unsigned int r = v.i + 0x7FFFu + ((v.i >> 16) & 1u);
  return (unsigned short)(r >> 16);
}
static __device__ __forceinline__ float bf2f(unsigned short u){
  union { unsigned int i; float f; } v; v.i = ((unsigned int)u) << 16; return v.f;
}
static __device__ __forceinline__ unsigned int pack2(float lo, float hi){
  return (unsigned int)f2bf(lo) | ((unsigned int)f2bf(hi) << 16);
}
static __device__ __forceinline__ unsigned int cvtpk(float lo, float hi){
  unsigned int d;
  asm("v_cvt_pk_bf16_f32 %0, %1, %2" : "=v"(d) : "v"(lo), "v"(hi));
  return d;
}

// async global -> LDS, 16 B per lane. LDS dest is wave-uniform base + lane*16;
// global source is per-lane.
static __device__ __forceinline__ void gload_lds16(const void* g, void* l){
  __builtin_amdgcn_global_load_lds(
      (const __attribute__((address_space(1))) void*)g,
      (__attribute__((address_space(3))) void*)l,
      16, 0, 0);
}

// ---------------- cast fp32 -> bf16, 8 elems/thread ----------------
__global__ void cast_f32_bf16(const float* __restrict__ src, uint4* __restrict__ dst, int n8){
  int stride = gridDim.x * blockDim.x;
  for (int i = blockIdx.x * blockDim.x + threadIdx.x; i < n8; i += stride){
    float4 a = ((const float4*)src)[2*i + 0];
    float4 b = ((const float4*)src)[2*i + 1];
    uint4 o;
    o.x = pack2(a.x, a.y); o.y = pack2(a.z, a.w);
    o.z = pack2(b.x, b.y); o.w = pack2(b.z, b.w);
    dst[i] = o;
  }
}

// ---------------- RoPE cos/sin table ----------------
__global__ void rope_table_kernel(const int* __restrict__ pos, float2* __restrict__ tab){
  int i = blockIdx.x * blockDim.x + threadIdx.x;
  if (i >= SL * 64) return;
  int s = i >> 6, f = i & 63;
  float inv = expf(-((float)(2 * f) / 128.0f) * 9.210340371976184f);
  float ang = (float)pos[s] * inv;
  float sn, cs;
  sincosf(ang, &sn, &cs);
  tab[i] = make_float2(cs, sn);
}

// ---------------- in-place RoPE on bf16 [s][stride] ----------------
__global__ void rope_apply_kernel(unsigned short* x, const float2* __restrict__ tab,
                                  int nheads, int rowstride){
  int i = blockIdx.x * blockDim.x + threadIdx.x;
  int total = SL * nheads * 64;
  if (i >= total) return;
  int f = i & 63;
  int t = i >> 6;
  int h = t % nheads;
  int s = t / nheads;
  float2 cs = tab[s * 64 + f];
  size_t base = (size_t)s * rowstride + h * HD;
  float x1 = bf2f(x[base + f]);
  float x2 = bf2f(x[base + f + 64]);
  x[base + f]      = f2bf(x1 * cs.x - x2 * cs.y);
  x[base + f + 64] = f2bf(x2 * cs.x + x1 * cs.y);
}

// ============ QKV GEMM: m201-depth 4-phase pipeline, BM=BN=256, BK=64 ============
// 8 waves (2M x 4N), per-wave 128x64 out. Phase quadrants (mh outer, nh inner):
// p1=(0,0) p2=(0,1) p3=(1,0) p4=(1,1), 16 MFMA each. Frag reuse: A[mh] read at
// p1/p3 held 2 phases; B[nh0] read p1 held for p3; B[nh1] read p2 held for p4.
// Staging runs 1 tile + 3 regions AHEAD: per tile t stage [p1: B1(t+1)->nxt,
// p2: A0(t+2)->cur, p3: B0(t+2)->cur, p4: A1(t+2)->cur]. Region-liveness makes
// the cur-buffer stores safe (each region's last LDS-read is >=1 phase earlier).
// ONE vmcnt(6) per tile at p4-end (3 regions in flight) -- never drains mid-loop.
__global__ __launch_bounds__(512, 2) void gemm_qkv4p(
  const unsigned short* __restrict__ A,   // [M][K]
  const unsigned short* __restrict__ B,   // [N][K]
  unsigned short* __restrict__ C,         // [M][N] bf16
  int M, int N, int K)
{
  __shared__ __align__(16) unsigned short As[2][256 * 64];
  __shared__ __align__(16) unsigned short Bs[2][256 * 64];
  const int tid = threadIdx.x;
  const int lane = tid & 63, wid = tid >> 6;
  const int g = lane >> 4, c15 = lane & 15;
  const int wr = wid >> 2, wn = wid & 3;

  // rect XCD swizzle (gx=24, gy=8 -> rect 8m x 3n per XCD)
  const int gx = gridDim.x, gy = gridDim.y;
  const int nwg = gx * gy;
  const int lin = blockIdx.y * gx + blockIdx.x;
  int mb, nb;
  const int cpx = nwg >> 3;
  const int RN  = cpx >> 3;
  if (RN > 0 && (gy & 7) == 0 && (cpx & 7) == 0 && gx % RN == 0 && (8 % (gx / RN)) == 0){
    int xcd = lin & 7, j = lin >> 3;
    int nrc = gx / RN;
    int rr = xcd / nrc, rc = xcd % nrc;
    mb = rr * 8 + (j & 7);
    nb = rc * RN + (j >> 3);
  } else { mb = lin / gx; nb = lin % gx; }
  const int m0 = mb * 256, n0 = nb * 256;

  // staging: one gload_lds inst = 8 rows x 128B per wave. lane l -> row l>>3,
  // LDS slot l&7; global source pre-applies inverse swizzle slot^(row&7).
  const int lr8 = lane >> 3;
  const int gsl = (lane & 7) ^ lr8;
  const unsigned short* Ag = A + (size_t)(m0 + lr8) * K + gsl * 8;
  const unsigned short* Bg = B + (size_t)(n0 + lr8) * K + gsl * 8;
  auto STA = [&](int b, int R, int t){ gload_lds16(Ag + (size_t)R * K + t * 64, &As[b][R * 64]); };
  auto STB = [&](int b, int R, int t){ gload_lds16(Bg + (size_t)R * K + t * 64, &Bs[b][R * 64]); };
  // per-wave region row bases (regions are 8-row-aligned -> row&7 preserved)
  const int aR0a = wid * 8,        aR0b = 128 + wid * 8;   // A region0 = rows {0-63,128-191}
  const int aR1a = 64 + wid * 8,   aR1b = 192 + wid * 8;   // A region1 = rows {64-127,192-255}
  const int bR0a = 64 * (wid >> 1) + 16 * (wid & 1), bR0b = bR0a + 8;  // B region0
  const int bR1a = bR0a + 32,      bR1b = bR0b + 32;                   // B region1

  auto ldA = [&](int b, int row, int kk) -> short8 {
    return *(const short8*)((const char*)&As[b][0] + row * 128 +
                            ((kk * 64 + g * 16) ^ ((c15 & 7) << 4)));
  };
  auto ldB = [&](int b, int row, int kk) -> short8 {
    return *(const short8*)((const char*)&Bs[b][0] + row * 128 +
                            ((kk * 64 + g * 16) ^ ((c15 & 7) << 4)));
  };

  f32x4 acc[8][4] = {};

  // prologue: tile0 complete (8 insts) + tile1 {A0, B0, A1} (6 insts, order = steady slots)
  STA(0, aR0a, 0); STA(0, aR0b, 0); STA(0, aR1a, 0); STA(0, aR1b, 0);
  STB(0, bR0a, 0); STB(0, bR0b, 0); STB(0, bR1a, 0); STB(0, bR1b, 0);
  STA(1, aR0a, 1); STA(1, aR0b, 1);
  STB(1, bR0a, 1); STB(1, bR0b, 1);
  STA(1, aR1a, 1); STA(1, aR1b, 1);
  asm volatile("s_waitcnt vmcnt(6)" ::: "memory");   // tile0 resident; t1.{A0,B0,A1} in flight
  __builtin_amdgcn_s_barrier();

  const int nk = K >> 6;
  short8 af[8], b0f[4], b1f[4];
  for (int t = 0; t < nk; ++t){
    const int cur = t & 1, nxt = cur ^ 1;
    const bool pf1 = (t + 1 < nk), pf2 = (t + 2 < nk);
    const int t1 = t + 1, t2 = t + 2;

    // ---------- p1: (mh0, nh0) ----------
#pragma unroll
    for (int m = 0; m < 4; ++m){
      int row = wr * 128 + m * 16 + c15;
      af[m * 2 + 0] = ldA(cur, row, 0); af[m * 2 + 1] = ldA(cur, row, 1);
    }
#pragma unroll
    for (int n = 0; n < 2; ++n){
      int row = wn * 64 + n * 16 + c15;
      b0f[n * 2 + 0] = ldB(cur, row, 0); b0f[n * 2 + 1] = ldB(cur, row, 1);
    }
    if (pf1){ STB(nxt, bR1a, t1); STB(nxt, bR1b, t1); }
    __builtin_amdgcn_s_barrier();
    __builtin_amdgcn_s_setprio(1);
#pragma unroll
    for (int m = 0; m < 4; ++m)
#pragma unroll
      for (int n = 0; n < 2; ++n){
        acc[m][n] = __builtin_amdgcn_mfma_f32_16x16x32_bf16(af[m*2+0], b0f[n*2+0], acc[m][n], 0, 0, 0);
        acc[m][n] = __builtin_amdgcn_mfma_f32_16x16x32_bf16(af[m*2+1], b0f[n*2+1], acc[m][n], 0, 0, 0);
      }
    __builtin_amdgcn_s_setprio(0);
    __builtin_amdgcn_s_barrier();

    // ---------- p2: (mh0, nh1) ----------
#pragma unroll
    for (int n = 0; n < 2; ++n){
      int row = wn * 64 + 32 + n * 16 + c15;
      b1f[n * 2 + 0] = ldB(cur, row, 0); b1f[n * 2 + 1] = ldB(cur, row, 1);
    }
    if (pf2){ STA(cur, aR0a, t2); STA(cur, aR0b, t2); }
    __builtin_amdgcn_s_barrier();
    __builtin_amdgcn_s_setprio(1);
#pragma unroll
    for (int m = 0; m < 4; ++m)
#pragma unroll
      for (int n = 0; n < 2; ++n){
        acc[m][2+n] = __builtin_amdgcn_mfma_f32_16x16x32_bf16(af[m*2+0], b1f[n*2+0], acc[m][2+n], 0, 0, 0);
        acc[m][2+n] = __builtin_amdgcn_mfma_f32_16x16x32_bf16(af[m*2+1], b1f[n*2+1], acc[m][2+n], 0, 0, 0);
      }
    __builtin_amdgcn_s_setprio(0);
    __builtin_amdgcn_s_barrier();

    // ---------- p3: (mh1, nh0) ----------
#pragma unroll
    for (int m = 0; m < 4; ++m){
      int row = wr * 128 + 64 + m * 16 + c15;
      af[m * 2 + 0] = ldA(cur, row, 0); af[m * 2 + 1] = ldA(cur, row, 1);
    }
    if (pf2){ STB(cur, bR0a, t2); STB(cur, bR0b, t2); }
    __builtin_amdgcn_s_barrier();
    __builtin_amdgcn_s_setprio(1);
#pragma unroll
    for (int m = 0; m < 4; ++m)
#pragma unroll
      for (int n = 0; n < 2; ++n){
        acc[4+m][n] = __builtin_amdgcn_mfma_f32_16x16x32_bf16(af[m*2+0], b0f[n*2+0], acc[4+m][n], 0, 0, 0);
        acc[4+m][n] = __builtin_amdgcn_mfma_f32_16x16x32_bf16(af[m*2+1], b0f[n*2+1], acc[4+m][n], 0, 0, 0);
      }
    __builtin_amdgcn_s_setprio(0);
    __builtin_amdgcn_s_barrier();

    // ---------- p4: (mh1, nh1) ----------
    if (pf2){ STA(cur, aR1a, t2); STA(cur, aR1b, t2); }
    __builtin_amdgcn_s_barrier();
    __builtin_amdgcn_s_setprio(1);
#pragma unroll
    for (int m = 0; m < 4; ++m)
#pragma unroll
      for (int n = 0; n < 2; ++n){
        acc[4+m][2+n] = __builtin_amdgcn_mfma_f32_16x16x32_bf16(af[m*2+0], b1f[n*2+0], acc[4+m][2+n], 0, 0, 0);
        acc[4+m][2+n] = __builtin_amdgcn_mfma_f32_16x16x32_bf16(af[m*2+1], b1f[n*2+1], acc[4+m][2+n], 0, 0, 0);
      }
    __builtin_amdgcn_s_setprio(0);
    if (pf2)      asm volatile("s_waitcnt vmcnt(6)" ::: "memory");
    else if (pf1) asm volatile("s_waitcnt vmcnt(0)" ::: "memory");
    __builtin_amdgcn_s_barrier();
  }

  // epilogue
#pragma unroll
  for (int fm = 0; fm < 8; ++fm)
#pragma unroll
    for (int fn = 0; fn < 4; ++fn){
      int row = m0 + wr * 128 + fm * 16 + g * 4;
      int col = n0 + wn * 64 + fn * 16 + c15;
      f32x4 v = acc[fm][fn];
#pragma unroll
      for (int r = 0; r < 4; ++r) C[(size_t)(row + r) * N + col] = f2bf(v[r]);
    }
}

// ========== bt-GEMM (proven round-5): C[M][N] = A[M][K] * B[N][K]^T ==========
template<bool F32OUT>
__global__ __launch_bounds__(256) void gemm_bt(
  const unsigned short* __restrict__ A,
  const unsigned short* __restrict__ B,
  void* __restrict__ Cp, int M, int N, int K)
{
  __shared__ __align__(16) unsigned short As[2][128 * 32];
  __shared__ __align__(16) unsigned short Bs[2][128 * 32];
  const int tid = threadIdx.x;
  const int lane = tid & 63, wid = tid >> 6;
  const int g = lane >> 4, c15 = lane & 15;
  const int wr = wid >> 1, wc = wid & 1;

  const int gx = gridDim.x, gy = gridDim.y;
  const int nwg = gx * gy;
  const int lin = blockIdx.y * gx + blockIdx.x;
  int mb, nb;
  const int cpx = nwg >> 3;
  const int RN  = cpx >> 3;
  if (RN > 0 && (gy & 7) == 0 && (cpx & 7) == 0 && gx % RN == 0 && (8 % (gx / RN)) == 0){
    int xcd = lin & 7, j = lin >> 3;
    int nrc = gx / RN;
    int rr = xcd / nrc, rc = xcd % nrc;
    mb = rr * 8 + (j & 7);
    nb = rc * RN + (j >> 3);
  } else { mb = lin / gx; nb = lin % gx; }
  const int m0 = mb * 128, n0 = nb * 128;

  const int srow = wid * 32 + (lane >> 2);
  const int scol = (lane & 3) * 8;
  const unsigned short* Ag = &A[(size_t)(m0 + srow) * K + scol];
  const unsigned short* Bg = &B[(size_t)(n0 + srow) * K + scol];
  const size_t K16 = (size_t)16 * K;

  f32x4 acc[4][4] = {};

  gload_lds16(Ag,       &As[0][wid * 1024]);
  gload_lds16(Ag + K16, &As[0][wid * 1024 + 512]);
  gload_lds16(Bg,       &Bs[0][wid * 1024]);
  gload_lds16(Bg + K16, &Bs[0][wid * 1024 + 512]);
  __syncthreads();

  const int nk = K >> 5;
  for (int t = 0; t < nk; ++t){
    const int cur = t & 1;
    if (t + 1 < nk){
      const unsigned short* a2 = Ag + (size_t)(t + 1) * 32;
      const unsigned short* b2 = Bg + (size_t)(t + 1) * 32;
      const int nb2 = cur ^ 1;
      gload_lds16(a2,       &As[nb2][wid * 1024]);
      gload_lds16(a2 + K16, &As[nb2][wid * 1024 + 512]);
      gload_lds16(b2,       &Bs[nb2][wid * 1024]);
      gload_lds16(b2 + K16, &Bs[nb2][wid * 1024 + 512]);
    }
    short8 af[4], bfr[4];
#pragma unroll
    for (int m = 0; m < 4; ++m)
      af[m] = *(const short8*)(&As[cur][(wr * 64 + m * 16 + c15) * 32 + g * 8]);
#pragma unroll
    for (int n = 0; n < 4; ++n)
      bfr[n] = *(const short8*)(&Bs[cur][(wc * 64 + n * 16 + c15) * 32 + g * 8]);
#pragma unroll
    for (int m = 0; m < 4; ++m)
#pragma unroll
      for (int n = 0; n < 4; ++n)
        acc[m][n] = __builtin_amdgcn_mfma_f32_16x16x32_bf16(af[m], bfr[n], acc[m][n], 0, 0, 0);
    __syncthreads();
  }

#pragma unroll
  for (int m = 0; m < 4; ++m)
#pragma unroll
    for (int n = 0; n < 4; ++n){
      int row = m0 + wr * 64 + m * 16 + g * 4;
      int col = n0 + wc * 64 + n * 16 + c15;
      f32x4 v = acc[m][n];
      if (F32OUT){
        float* C = (float*)Cp;
#pragma unroll
        for (int r = 0; r < 4; ++r) C[(size_t)(row + r) * N + col] = v[r];
      } else {
        unsigned short* C = (unsigned short*)Cp;
#pragma unroll
        for (int r = 0; r < 4; ++r) C[(size_t)(row + r) * N + col] = f2bf(v[r]);
      }
    }
}

// ---------------- V transpose: v[s][h*128+d] (stride vstride) -> vt[h][d][s] ----------------
__global__ void transpose_v_kernel(const unsigned short* __restrict__ v, int vstride,
                                   unsigned short* __restrict__ vt){
  __shared__ unsigned short t[64][65];
  int h  = blockIdx.z;
  int d0 = blockIdx.y * 64;
  int s0 = blockIdx.x * 64;
  int c  = threadIdx.x & 63;
  int r0 = threadIdx.x >> 6;
#pragma unroll
  for (int r = r0; r < 64; r += 4) t[r][c] = v[(size_t)(s0 + r) * vstride + h * HD + d0 + c];
  __syncthreads();
#pragma unroll
  for (int r = r0; r < 64; r += 4) vt[(size_t)(h * HD + d0 + r) * SL + s0 + c] = t[c][r];
}

// ---------------- flash attention: swapped-QK in-register softmax ----------------
__global__ __launch_bounds__(512, 4) void flash_attn_kernel(
  const unsigned short* __restrict__ Q,    // row stride QKVN
  const unsigned short* __restrict__ Kb,   // row stride QKVN
  const unsigned short* __restrict__ Vt,   // [kvh*128+d][SL]
  unsigned short* __restrict__ O)          // row stride HID
{
  __shared__ __align__(16) unsigned short Ks[64 * 128];    // stride 256 B, XOR-swizzled
  __shared__ __align__(16) unsigned short Vs[128 * 64];    // stride 128 B, XOR-swizzled
  const int tid = threadIdx.x, lane = tid & 63, wid = tid >> 6;
  const int g = lane >> 4, c15 = lane & 15;
  const int kvh = blockIdx.x;
  const int yy = blockIdx.y;
  const int qb = (yy & 1) ? (yy >> 1) : (63 - (yy >> 1));   // heavy/light interleave
  const int h = kvh * 4 + (wid & 3);
  const int rg = wid >> 2;
  const int q0 = qb * 32;
  const int qg = q0 + rg * 16 + c15;       // this lane's q row

  short8 aq[4];
  {
    size_t qrow = (size_t)qg * QKVN + h * HD;
#pragma unroll
    for (int kk = 0; kk < 4; ++kk)
      aq[kk] = *(const short8*)(&Q[qrow + kk * 32 + g * 8]);
  }

  const int krow = tid >> 3, kcol = (tid & 7) * 8;
  const int vrow = tid >> 2, vcol = (tid & 3) * 8;
  const unsigned short* Kgb = Kb + (size_t)kvh * HD;
  const unsigned short* Vgb = Vt + ((size_t)kvh * HD + vrow) * SL;

  uint4 kr0, kr1, vr0, vr1;
  {
    const unsigned short* kg = Kgb + (size_t)krow * QKVN + kcol;
    kr0 = *(const uint4*)kg; kr1 = *(const uint4*)(kg + 64);
    const unsigned short* vg = Vgb + vcol;
    vr0 = *(const uint4*)vg; vr1 = *(const uint4*)(vg + 32);
  }

  float m_i = -1e30f, l_i = 0.f;
  f32x4 oacc[8];
#pragma unroll
  for (int df = 0; df < 8; ++df) oacc[df] = (f32x4){0.f, 0.f, 0.f, 0.f};

  const float scl2 = 0.08838834764831845f * 1.4426950408889634f;  // 1/sqrt(128)*log2e
  const int nt = (q0 + 31) / 64 + 1;
  for (int kt = 0; kt < nt; ++kt){
    *(uint4*)((char*)Ks + krow * 256 + (( kcol * 2       ) ^ ((krow & 7) << 4))) = kr0;
    *(uint4*)((char*)Ks + krow * 256 + (((kcol * 2) + 128) ^ ((krow & 7) << 4))) = kr1;
    *(uint4*)((char*)Vs + vrow * 128 + (( vcol * 2       ) ^ ((vrow & 7) << 4))) = vr0;
    *(uint4*)((char*)Vs + vrow * 128 + (((vcol * 2) +  64) ^ ((vrow & 7) << 4))) = vr1;
    __syncthreads();

    if (kt + 1 < nt){
      const unsigned short* kg = Kgb + (size_t)((kt + 1) * 64 + krow) * QKVN + kcol;
      kr0 = *(const uint4*)kg; kr1 = *(const uint4*)(kg + 64);
      const unsigned short* vg = Vgb + (kt + 1) * 64 + vcol;
      vr0 = *(const uint4*)vg; vr1 = *(const uint4*)(vg + 32);
    }

    // S^T = K Q : lane holds q=c15, kv = f*16 + g*4 + r
    f32x4 sc[4];
    __builtin_amdgcn_s_setprio(1);
#pragma unroll
    for (int f = 0; f < 4; ++f){
      sc[f] = (f32x4){0.f, 0.f, 0.f, 0.f};
#pragma unroll
      for (int kk = 0; kk < 4; ++kk){
        short8 bk = *(const short8*)((const char*)Ks + (f * 16 + c15) * 256 +
                                     ((kk * 64 + g * 16) ^ ((c15 & 7) << 4)));
        sc[f] = __builtin_amdgcn_mfma_f32_16x16x32_bf16(bk, aq[kk], sc[f], 0, 0, 0);
      }
    }
    __builtin_amdgcn_s_setprio(0);

    float p[4][4];
#pragma unroll
    for (int f = 0; f < 4; ++f)
#pragma unroll
      for (int r = 0; r < 4; ++r){
        int kvg = kt * 64 + f * 16 + g * 4 + r;
        p[f][r] = (kvg <= qg) ? sc[f][r] * scl2 : -1e30f;
      }

    float pmax = p[0][0];
#pragma unroll
    for (int f = 0; f < 4; ++f)
#pragma unroll
      for (int r = 0; r < 4; ++r) pmax = fmaxf(pmax, p[f][r]);
    pmax = fmaxf(pmax, __shfl_xor(pmax, 16, 64));
    pmax = fmaxf(pmax, __shfl_xor(pmax, 32, 64));

    if (!__all(pmax - m_i <= 8.0f)){
      float mnew = fmaxf(m_i, pmax);
      float cf = exp2f(m_i - mnew);
      float cfr[4];
#pragma unroll
      for (int r = 0; r < 4; ++r) cfr[r] = __shfl(cf, (lane & 48) | (g * 4 + r), 64);
#pragma unroll
      for (int df = 0; df < 8; ++df)
#pragma unroll
        for (int r = 0; r < 4; ++r) oacc[df][r] *= cfr[r];
      l_i *= cf;
      m_i = mnew;
    }

    float lsum = 0.f;
#pragma unroll
    for (int f = 0; f < 4; ++f)
#pragma unroll
      for (int r = 0; r < 4; ++r){ float e = exp2f(p[f][r] - m_i); p[f][r] = e; lsum += e; }
    lsum += __shfl_xor(lsum, 16, 64);
    lsum += __shfl_xor(lsum, 32, 64);
    l_i += lsum;

    unsigned int pd[4][2];
#pragma unroll
    for (int f = 0; f < 4; ++f){
      pd[f][0] = cvtpk(p[f][0], p[f][1]);
      pd[f][1] = cvtpk(p[f][2], p[f][3]);
    }

    const int src0 = ((g & 1) << 5) | c15;
    const int src1 = src0 + 16;
    const bool hiF = (g >= 2);
#pragma unroll
    for (int kk = 0; kk < 2; ++kk){
      union { unsigned int u[4]; short8 s8; } pa;
#pragma unroll
      for (int pr = 0; pr < 2; ++pr){
        unsigned int a0 = __shfl((int)pd[2 * kk + 0][pr], src0, 64);
        unsigned int b0 = __shfl((int)pd[2 * kk + 1][pr], src0, 64);
        unsigned int a1 = __shfl((int)pd[2 * kk + 0][pr], src1, 64);
        unsigned int b1 = __shfl((int)pd[2 * kk + 1][pr], src1, 64);
        pa.u[pr]     = hiF ? b0 : a0;
        pa.u[2 + pr] = hiF ? b1 : a1;
      }
      __builtin_amdgcn_s_setprio(1);
#pragma unroll
      for (int df = 0; df < 8; ++df){
        short8 bv = *(const short8*)((const char*)Vs + (df * 16 + c15) * 128 +
                                     ((kk * 64 + g * 16) ^ ((c15 & 7) << 4)));
        oacc[df] = __builtin_amdgcn_mfma_f32_16x16x32_bf16(pa.s8, bv, oacc[df], 0, 0, 0);
      }
      __builtin_amdgcn_s_setprio(0);
    }
    __syncthreads();
  }

  float lr[4];
#pragma unroll
  for (int r = 0; r < 4; ++r) lr[r] = __shfl(l_i, (lane & 48) | (g * 4 + r), 64);
#pragma unroll
  for (int df = 0; df < 8; ++df)
#pragma unroll
    for (int r = 0; r < 4; ++r){
      int row = q0 + rg * 16 + g * 4 + r;
      O[(size_t)row * HID + h * HD + df * 16 + c15] = f2bf(oacc[df][r] / lr[r]);
    }
}

extern "C" void kernel_launch(void* const* d_in, const int* in_sizes, int n_in,
                              void* d_out, int out_size, void* d_ws, size_t ws_size,
                              hipStream_t stream)
{
  const float* hs  = (const float*)d_in[0];
  const float* qw  = (const float*)d_in[1];
  const float* kw  = (const float*)d_in[2];
  const float* vw  = (const float*)d_in[3];
  const float* ow  = (const float*)d_in[4];
  const int*   pos = (const int*)d_in[5];

  char* w = (char*)d_ws;
  auto alloc = [&](size_t bytes){ char* p = w; w += (bytes + 255) & ~(size_t)255; return p; };
  unsigned short* xb   = (unsigned short*)alloc((size_t)SL * HID * 2);
  unsigned short* wqkv = (unsigned short*)alloc((size_t)QKVN * HID * 2);
  unsigned short* owb  = (unsigned short*)alloc((size_t)HID * HID * 2);
  unsigned short* qkv  = (unsigned short*)alloc((size_t)SL * QKVN * 2);
  unsigned short* vt   = (unsigned short*)alloc((size_t)SL * KVW * 2);
  unsigned short* ab   = (unsigned short*)alloc((size_t)SL * HID * 2);
  float2*         tab  = (float2*)alloc((size_t)SL * 64 * sizeof(float2));

  auto cast = [&](const float* s, unsigned short* d, long n){
    int n8 = (int)(n / 8);
    int blocks = (n8 + 255) / 256; if (blocks > 2048) blocks = 2048;
    cast_f32_bf16<<<blocks, 256, 0, stream>>>(s, (uint4*)d, n8);
  };
  cast(hs, xb, (long)SL * HID);
  cast(qw, wqkv,                              (long)HID * HID);
  cast(kw, wqkv + (size_t)HID * HID,          (long)KVW * HID);
  cast(vw, wqkv + (size_t)(HID + KVW) * HID,  (long)KVW * HID);
  cast(ow, owb,                               (long)HID * HID);

  rope_table_kernel<<<(SL * 64 + 255) / 256, 256, 0, stream>>>(pos, tab);

  // fused QKV projection: [2048][6144] = xb @ wqkv^T  (grid 24 x 8 = 192, 4-phase engine)
  gemm_qkv4p<<<dim3(QKVN / 256, SL / 256), 512, 0, stream>>>(xb, wqkv, qkv, SL, QKVN, HID);

  rope_apply_kernel<<<(SL * NH  * 64 + 255) / 256, 256, 0, stream>>>(qkv,        tab, NH,  QKVN);
  rope_apply_kernel<<<(SL * NKV * 64 + 255) / 256, 256, 0, stream>>>(qkv + HID,  tab, NKV, QKVN);

  transpose_v_kernel<<<dim3(SL / 64, HD / 64, NKV), 256, 0, stream>>>(qkv + HID + KVW, QKVN, vt);

  // grid: 8 KV groups x 64 q-blocks of 32 rows
  flash_attn_kernel<<<dim3(NKV, SL / 32), 512, 0, stream>>>(qkv, qkv + HID, vt, ab);

  // O projection: proven round-5 engine (grid 32 x 16)
  gemm_bt<true><<<dim3(HID / 128, SL / 128), 256, 0, stream>>>(ab, owb, d_out, SL, HID, HID);
}